// Round 1
// 158.354 us; speedup vs baseline: 1.0028x; 1.0028x over previous
//
#include <hip/hip_runtime.h>
#include <hip/hip_bf16.h>

#define NE 32
#define MM 1024
#define KK 512
#define NN 512
#define BM 64    // rows per tile (finer valid-mask granularity, 16 m-slots/expert)
#define BN 128   // cols per tile -> 4 n-tiles
#define BK 32    // bf16 elems per LDS row = 64 B = 4 x 16B units, XOR-swizzled

typedef __attribute__((ext_vector_type(8))) short bf16x8;
typedef __attribute__((ext_vector_type(4))) float floatx4;

__device__ __forceinline__ short f2bf(float f) {
  union { __hip_bfloat16 b; short s; } u;
  u.b = __float2bfloat16(f);   // RNE
  return u.s;
}

// One item per block, decoded from cnts (no queue/atomics/prepass):
//   items [0, 4*sum(vt))      : GEMM tiles (64x128), expert-major, mt-major, nt fastest
//   items [4*sum(vt), total)  : zero-fill 64x512 stripes (rows >= cnt)
//   total = 512 + 3*sum(vt) <= 2048 always -> grid 2048 covers everything,
//   and gives ~8 blocks/CU of dispatch backfill for tail balance.
extern "C" __global__ __launch_bounds__(256, 3)
void expert_gemm(const float* __restrict__ A, const float* __restrict__ B,
                 const int* __restrict__ cnts, float* __restrict__ C)
{
  const int b   = blockIdx.x;
  const int tid = threadIdx.x;

  int e = -1, mt = 0, nt = 0;
  int acc = 0;
#pragma unroll 1
  for (int i = 0; i < NE; ++i) {
    int vt = (cnts[i] + BM - 1) >> 6;   // 64-row tiles
    int c4 = vt << 2;                   // 4 n-tiles each
    if (e < 0 && b < acc + c4) { int r = b - acc; e = i; mt = r >> 2; nt = r & 3; }
    acc += c4;
  }
  if (e < 0) {
    int z = b - acc, a2 = 0;
#pragma unroll 1
    for (int i = 0; i < NE; ++i) {
      int vt = (cnts[i] + BM - 1) >> 6;
      int c = 16 - vt;
      if (e < 0 && z < a2 + c) { e = i; mt = vt + (z - a2); }
      a2 += c;
    }
    if (e < 0) return;   // beyond total item count
    // zero-fill a 64x512 stripe (harness poisons d_out to 0xAA each launch)
    float* Ce = C + ((size_t)e * MM + mt * BM) * NN;
    float4 zf = make_float4(0.f, 0.f, 0.f, 0.f);
#pragma unroll
    for (int i = 0; i < 32; ++i) {
      int fidx = i * 256 + tid;
      int r = fidx >> 7, c = (fidx & 127) << 2;
      *(float4*)(Ce + (size_t)r * NN + c) = zf;
    }
    return;
  }

  // ---- GEMM tile: C[e][m0:m0+64][n0:n0+128] = A[e] @ B[e]^T ----
  const int m0 = mt * BM, n0 = nt * BN;
  const int cnt = cnts[e];
  const float* Ae = A + ((size_t)e * MM + m0) * KK;
  const float* Be = B + ((size_t)e * NN + n0) * KK;
  float* Ce = C + ((size_t)e * MM + m0) * NN + n0;

  // Swizzled LDS: row r is 4 units of 16 B; unit u stored at physical
  // unit (r*4 + (u ^ (r&3))). Both ds_write_b128 and ds_read_b128 hit
  // the 8-phase LDS BW floor with zero bank conflicts (verified prior session).
  __shared__ __align__(16) short lA[BM * BK];  // 4 KB
  __shared__ __align__(16) short lB[BN * BK];  // 8 KB

  const int wave = tid >> 6, lane = tid & 63;
  const int wm = (wave >> 1) * 32, wn = (wave & 1) * 64;  // wave tile: 32x64
  const int fr = lane & 15, kh = lane >> 4;

  const int sr = tid >> 2;   // staging row (A: row sr; B: rows sr and sr+64)
  const int su = tid & 3;    // 16B unit within row -> floats [su*8, su*8+8)

  floatx4 acc4[2][4] = {};

  // Register-prefetch double buffer: loads for slab kt+1 issue at the top of
  // iteration kt, BEFORE the vmcnt wait on slab kt -> memory stays in flight
  // across the convert/LDS/MFMA phases (prefetch distance = 1 full iteration).
  float4 ra[2], rbv[4], na[2], nb[4];

#define ISSUE(pa, pb, kt_) do {                                          \
    int col_ = (kt_) + (su << 3);                                        \
    pa[0] = *(const float4*)(Ae + (size_t)sr * KK + col_);               \
    pa[1] = *(const float4*)(Ae + (size_t)sr * KK + col_ + 4);           \
    pb[0] = *(const float4*)(Be + (size_t)sr * KK + col_);               \
    pb[1] = *(const float4*)(Be + (size_t)sr * KK + col_ + 4);           \
    pb[2] = *(const float4*)(Be + (size_t)(sr + 64) * KK + col_);        \
    pb[3] = *(const float4*)(Be + (size_t)(sr + 64) * KK + col_ + 4);    \
  } while (0)

  ISSUE(ra, rbv, 0);

#pragma unroll
  for (int kt = 0; kt < KK; kt += BK) {
    if (kt + BK < KK) ISSUE(na, nb, kt + BK);   // static under full unroll

    // convert current slab (vmcnt wait lands here, one full iteration after issue)
    bf16x8 va  = { f2bf(ra[0].x),  f2bf(ra[0].y),  f2bf(ra[0].z),  f2bf(ra[0].w),
                   f2bf(ra[1].x),  f2bf(ra[1].y),  f2bf(ra[1].z),  f2bf(ra[1].w) };
    bf16x8 vb0 = { f2bf(rbv[0].x), f2bf(rbv[0].y), f2bf(rbv[0].z), f2bf(rbv[0].w),
                   f2bf(rbv[1].x), f2bf(rbv[1].y), f2bf(rbv[1].z), f2bf(rbv[1].w) };
    bf16x8 vb1 = { f2bf(rbv[2].x), f2bf(rbv[2].y), f2bf(rbv[2].z), f2bf(rbv[2].w),
                   f2bf(rbv[3].x), f2bf(rbv[3].y), f2bf(rbv[3].z), f2bf(rbv[3].w) };

    __syncthreads();   // previous iteration's ds_reads complete before overwrite
    {
      int u0 = (sr << 2) + (su ^ (sr & 3));
      *(bf16x8*)(lA + (u0 << 3)) = va;
      *(bf16x8*)(lB + (u0 << 3)) = vb0;
      int r1 = sr + 64;
      int u1 = (r1 << 2) + (su ^ (r1 & 3));
      *(bf16x8*)(lB + (u1 << 3)) = vb1;
    }
    __syncthreads();

    bf16x8 af[2], bfv[4];
#pragma unroll
    for (int i = 0; i < 2; ++i) {
      int rA = wm + (i << 4) + fr;
      af[i]  = *(const bf16x8*)(lA + ((((rA << 2) + (kh ^ (rA & 3)))) << 3));
    }
#pragma unroll
    for (int j = 0; j < 4; ++j) {
      int rB = wn + (j << 4) + fr;
      bfv[j] = *(const bf16x8*)(lB + ((((rB << 2) + (kh ^ (rB & 3)))) << 3));
    }
#pragma unroll
    for (int i = 0; i < 2; ++i)
#pragma unroll
      for (int j = 0; j < 4; ++j)
        acc4[i][j] = __builtin_amdgcn_mfma_f32_16x16x32_bf16(af[i], bfv[j], acc4[i][j], 0, 0, 0);

    // rotate prefetch buffers (renamed away by full unroll)
#pragma unroll
    for (int q = 0; q < 2; ++q) ra[q] = na[q];
#pragma unroll
    for (int q = 0; q < 4; ++q) rbv[q] = nb[q];
  }
#undef ISSUE

  // epilogue: C/D layout col=lane&15, row=(lane>>4)*4+reg (m89/m91-verified)
  const int rbase = (lane >> 4) * 4;
#pragma unroll
  for (int i = 0; i < 2; ++i) {
#pragma unroll
    for (int r = 0; r < 4; ++r) {
      int row = wm + i * 16 + rbase + r;
      bool valid = (m0 + row) < cnt;
#pragma unroll
      for (int j = 0; j < 4; ++j) {
        int col = wn + j * 16 + fr;
        Ce[(size_t)row * NN + col] = valid ? acc4[i][j][r] : 0.0f;
      }
    }
  }
}

extern "C" void kernel_launch(void* const* d_in, const int* in_sizes, int n_in,
                              void* d_out, int out_size, void* d_ws, size_t ws_size,
                              hipStream_t stream) {
  const float* A    = (const float*)d_in[0];
  const float* B    = (const float*)d_in[1];
  const int*   cnts = (const int*)d_in[2];
  float*       C    = (float*)d_out;

  // total items = 512 + 3*sum(vt) <= 2048 structurally; one item per block
  hipLaunchKernelGGL(expert_gemm, dim3(2048), dim3(256), 0, stream, A, B, cnts, C);
}